// Round 10
// baseline (159.523 us; speedup 1.0000x reference)
//
#include <hip/hip_runtime.h>
#include <hip/hip_bf16.h>

#define B_  2
#define S_  512
#define H_  8
#define D_  32
#define DM_ 256
#define HD_ 256
#define NROW 4
#define TI  2          // i-rows per attention block
#define HC  2          // heads per attention block
#define NR  (TI * HC)  // p-rows per block
#define JC  32         // j-columns per DMA chunk

// ---------------------------------------------------------------------------
// Kernel A: QKV projection.  grid = (B*S/NROW, 3), block = 256.
// out layout: (b, h, s, d).  q is pre-scaled by 1/sqrt(D).
// ---------------------------------------------------------------------------
__global__ __launch_bounds__(256) void qkv_kernel(
    const float* __restrict__ hid, const float* __restrict__ wq,
    const float* __restrict__ wk, const float* __restrict__ wv,
    float* __restrict__ qo, float* __restrict__ ko, float* __restrict__ vo)
{
  __shared__ float hs[NROW][DM_];
  const int r0 = blockIdx.x * NROW;                 // global row in [0, B*S)
  const float* w   = (blockIdx.y == 0) ? wq : (blockIdx.y == 1) ? wk : wv;
  float*       out = (blockIdx.y == 0) ? qo : (blockIdx.y == 1) ? ko : vo;
  const float mulf = (blockIdx.y == 0) ? 0.17677669529663687f : 1.0f;
  const int tid = threadIdx.x;

  for (int idx = tid; idx < NROW * DM_; idx += 256)
    hs[idx >> 8][idx & 255] = hid[r0 * DM_ + idx];
  __syncthreads();

  float acc[NROW] = {0.f, 0.f, 0.f, 0.f};
  const float* wp = w + tid;                        // column m = tid
  #pragma unroll 8
  for (int c4 = 0; c4 < DM_ / 4; ++c4) {
    const float w0 = wp[(4 * c4 + 0) * HD_];
    const float w1 = wp[(4 * c4 + 1) * HD_];
    const float w2 = wp[(4 * c4 + 2) * HD_];
    const float w3 = wp[(4 * c4 + 3) * HD_];
    #pragma unroll
    for (int r = 0; r < NROW; ++r) {
      const float4 hv = reinterpret_cast<const float4*>(&hs[r][0])[c4];
      acc[r] = fmaf(hv.x, w0, acc[r]);
      acc[r] = fmaf(hv.y, w1, acc[r]);
      acc[r] = fmaf(hv.z, w2, acc[r]);
      acc[r] = fmaf(hv.w, w3, acc[r]);
    }
  }
  const int h = tid >> 5, d = tid & 31;
  #pragma unroll
  for (int r = 0; r < NROW; ++r) {
    const int g = r0 + r;
    const int b = g >> 9, s = g & (S_ - 1);
    out[((b * H_ + h) * S_ + s) * D_ + d] = acc[r] * mulf;
  }
}

// 8-lane (octet) sum via DPP (VALU pipe).  Valid at lanes with (lane&7)==0.
__device__ __forceinline__ float red8(float x) {
  int i;
  i = __builtin_amdgcn_mov_dpp(__float_as_int(x), 0xB1, 0xf, 0xf, true); // quad_perm xor1
  x += __int_as_float(i);
  i = __builtin_amdgcn_mov_dpp(__float_as_int(x), 0x4E, 0xf, 0xf, true); // quad_perm xor2
  x += __int_as_float(i);
  i = __builtin_amdgcn_mov_dpp(__float_as_int(x), 0x124, 0xf, 0xf, true); // row_ror:4
  x += __int_as_float(i);
  return x;
}

// async global->LDS 16B per lane; dst is the wave-uniform base (HW adds lane*16)
__device__ __forceinline__ void lds_dma16(float* dst_uniform, const float* src) {
  __builtin_amdgcn_global_load_lds(
      (const __attribute__((address_space(1))) unsigned int*)src,
      (__attribute__((address_space(3))) unsigned int*)dst_uniform,
      16, 0, 0);
}

// ---------------------------------------------------------------------------
// Kernel B: scores + mask + softmax + attn@V.
// rpe is streamed via double-buffered global_load_lds (width=16): the DMA
// queue holds in-flight data, sidestepping the compiler's refusal to keep
// batched loads in VGPRs (r8/r9: VGPR=28 -> 1-2 loads in flight -> latency
// serialization).  2048 blocks (XCD swizzle keeps the 4 head-group twins of
// one rpe tile on one XCD for L2 reuse), 256 thr, 6 blocks/CU (24.6 KB LDS).
// LDS chunk layout, 16B unit u = ii*256 + j_loc*8 + dc  (ii<TI, j_loc<JC,
// dc<8); DMA wave-instr m in [0,8): lane l -> unit m*64+l, global
// (ii=m>>2, j_loc=(m&3)*8+(l>>3), dc=l&7).  Compute thread (j_loc=tid>>3,
// dc=tid&7) reads units at float offset 4*(tid) and 4*(256+tid): lane-
// contiguous ds_read_b128 (conflict-optimal).  K in constant-indexed VGPRs.
// scores[h,i,j] = sum_d q'[h,j,d] k[h,i,d] rpe[i,j,d]  (q' pre-scaled);
// mask: j < station OR j == i.  p-row r = hh*TI + ii.
// ---------------------------------------------------------------------------
__global__ __launch_bounds__(256, 6) void attn_kernel(
    const float* __restrict__ rpe, const float* __restrict__ q_ws,
    const float* __restrict__ k_ws, const float* __restrict__ v_ws,
    const int* __restrict__ station_p, float* __restrict__ o_ws)
{
  __shared__ __align__(16) float rpe_smem[2][TI * JC * D_];  // 2 x 8 KB
  __shared__ __align__(16) float p_smem[NR * S_];            // 8 KB; reused as redv
  __shared__ float sums[NR];

  const int tid  = threadIdx.x;
  const int w    = tid >> 6, lane = tid & 63;
  const int jl   = tid >> 3;                       // 0..31 (score mapping)
  const int dc   = tid & 7;
  const int j8   = lane >> 3;                      // attn@V mapping
  const int n    = blockIdx.x;                     // 0..2047
  const int hg   = (n >> 3) & 3;
  const int t    = (n & 7) | ((n >> 5) << 3);      // 0..511 tile id
  const int b    = t >> 8;
  const int i0   = (t & 255) * TI;
  const int h0   = hg * HC;
  const int HS   = S_ * D_;                        // head / i-row stride

  int station = station_p[0];
  station = station > S_ ? S_ : (station < 0 ? 0 : station);
  const int NC = (station + JC - 1) / JC;          // chunks of 32 j-cols

  const float* qb = q_ws + (size_t)((b * H_ + h0) * S_) * D_;
  const float* kb = k_ws + (size_t)((b * H_ + h0) * S_ + i0) * D_;
  const float* vb = v_ws + (size_t)((b * H_ + h0) * S_) * D_;
  const float* rb = rpe + ((size_t)b * S_ + i0) * S_ * D_;

  // K fragments (constant indices only — r7 lesson): 16B chunk dc of each row
  float4 kf[HC][TI];
  #pragma unroll
  for (int hh = 0; hh < HC; ++hh)
    #pragma unroll
    for (int ii = 0; ii < TI; ++ii)
      kf[hh][ii] = *reinterpret_cast<const float4*>(kb + hh * HS + ii * D_ + dc * 4);

  // ---- prologue: DMA chunk 0 ----
  if (NC > 0) {
    #pragma unroll
    for (int it = 0; it < 2; ++it) {
      const int m = w * 2 + it;                    // wave-uniform
      const float* src = rb + (m >> 2) * HS
                       + (size_t)(((m & 3) * 8) + (lane >> 3)) * D_ + (lane & 7) * 4;
      lds_dma16(&rpe_smem[0][m * 256], src);
    }
  }
  __syncthreads();

  // ---- score chunks: compute c from LDS while DMA streams c+1 ----
  for (int c = 0; c < NC; ++c) {
    if (c + 1 < NC) {
      const int jb = (c + 1) * JC;
      #pragma unroll
      for (int it = 0; it < 2; ++it) {
        const int m = w * 2 + it;
        const float* src = rb + (m >> 2) * HS
                         + (size_t)(jb + ((m & 3) * 8) + (lane >> 3)) * D_ + (lane & 7) * 4;
        lds_dma16(&rpe_smem[(c + 1) & 1][m * 256], src);
      }
    }
    const float* buf = rpe_smem[c & 1];
    const int j = c * JC + jl;                     // < S_ always (NC <= 16)
    const float4 rv0 = *reinterpret_cast<const float4*>(buf + tid * 4);
    const float4 rv1 = *reinterpret_cast<const float4*>(buf + (256 + tid) * 4);
    const float4 q0 = *reinterpret_cast<const float4*>(qb + (size_t)j * D_ + dc * 4);
    const float4 q1 = *reinterpret_cast<const float4*>(qb + HS + (size_t)j * D_ + dc * 4);
    const bool st = (dc == 0) && (j < station);

    float s;
    s = q0.x * kf[0][0].x * rv0.x;
    s = fmaf(q0.y * kf[0][0].y, rv0.y, s);
    s = fmaf(q0.z * kf[0][0].z, rv0.z, s);
    s = fmaf(q0.w * kf[0][0].w, rv0.w, s);
    s = red8(s);
    if (st) p_smem[0 * S_ + j] = s;

    s = q0.x * kf[0][1].x * rv1.x;
    s = fmaf(q0.y * kf[0][1].y, rv1.y, s);
    s = fmaf(q0.z * kf[0][1].z, rv1.z, s);
    s = fmaf(q0.w * kf[0][1].w, rv1.w, s);
    s = red8(s);
    if (st) p_smem[1 * S_ + j] = s;

    s = q1.x * kf[1][0].x * rv0.x;
    s = fmaf(q1.y * kf[1][0].y, rv0.y, s);
    s = fmaf(q1.z * kf[1][0].z, rv0.z, s);
    s = fmaf(q1.w * kf[1][0].w, rv0.w, s);
    s = red8(s);
    if (st) p_smem[2 * S_ + j] = s;

    s = q1.x * kf[1][1].x * rv1.x;
    s = fmaf(q1.y * kf[1][1].y, rv1.y, s);
    s = fmaf(q1.z * kf[1][1].z, rv1.z, s);
    s = fmaf(q1.w * kf[1][1].w, rv1.w, s);
    s = red8(s);
    if (st) p_smem[3 * S_ + j] = s;

    __syncthreads();   // drains DMA for c+1; orders buf reuse
  }

  // ---- diag cells beyond station (wave 0, lanes 0..15: ii=lane>>3, dc) ----
  if (w == 0 && lane < TI * 8) {
    const int ii = lane >> 3;
    const int j = i0 + ii;
    if (j >= station) {
      const float4 rv = *reinterpret_cast<const float4*>(
          rb + ii * HS + (size_t)j * D_ + dc * 4);
      #pragma unroll
      for (int hh = 0; hh < HC; ++hh) {
        const float4 q4 = *reinterpret_cast<const float4*>(
            qb + hh * HS + (size_t)j * D_ + dc * 4);
        const float4 k4 = *reinterpret_cast<const float4*>(
            kb + hh * HS + ii * D_ + dc * 4);
        float s = q4.x * k4.x * rv.x;
        s = fmaf(q4.y * k4.y, rv.y, s);
        s = fmaf(q4.z * k4.z, rv.z, s);
        s = fmaf(q4.w * k4.w, rv.w, s);
        s = red8(s);
        if (dc == 0) p_smem[(hh * TI + ii) * S_ + j] = s;
      }
    }
  }
  __syncthreads();

  // ---- softmax: wave w handles p-row w (NR == 4 rows) ----
  {
    const int r  = w;
    const int ii = r & (TI - 1);
    const int ig = i0 + ii;
    const bool dx = (ig >= station);
    float m = -1e30f;
    for (int jj = lane; jj < station; jj += 64) m = fmaxf(m, p_smem[r * S_ + jj]);
    const float dv = dx ? p_smem[r * S_ + ig] : -1e30f;
    m = fmaxf(m, dv);
    #pragma unroll
    for (int o = 32; o; o >>= 1) m = fmaxf(m, __shfl_xor(m, o, 64));
    float sum = 0.f;
    for (int jj = lane; jj < station; jj += 64) {
      const float e = __expf(p_smem[r * S_ + jj] - m);
      p_smem[r * S_ + jj] = e;
      sum += e;
    }
    #pragma unroll
    for (int o = 32; o; o >>= 1) sum += __shfl_xor(sum, o, 64);
    if (dx) {
      const float e = __expf(dv - m);
      sum += e;
      if (lane == 0) p_smem[r * S_ + ig] = e;
    }
    if (lane == 0) sums[r] = sum;
  }
  __syncthreads();

  // ---- attn @ V: thread (j8,dc) accumulates its j-slice, both heads ----
  float4 acc[HC][TI];
  #pragma unroll
  for (int hh = 0; hh < HC; ++hh)
    #pragma unroll
    for (int ii = 0; ii < TI; ++ii) acc[hh][ii] = make_float4(0.f, 0.f, 0.f, 0.f);

  for (int jb = w * 8; jb < station; jb += 32) {
    const int j  = jb + j8;
    const int jc = j < S_ ? j : S_ - 1;
    float4 v4[HC];
    #pragma unroll
    for (int hh = 0; hh < HC; ++hh)
      v4[hh] = *reinterpret_cast<const float4*>(vb + hh * HS + jc * D_ + dc * 4);
    #pragma unroll
    for (int hh = 0; hh < HC; ++hh)
      #pragma unroll
      for (int ii = 0; ii < TI; ++ii) {
        float pv = 0.f;
        if (j < station) pv = p_smem[(hh * TI + ii) * S_ + j];
        acc[hh][ii].x = fmaf(pv, v4[hh].x, acc[hh][ii].x);
        acc[hh][ii].y = fmaf(pv, v4[hh].y, acc[hh][ii].y);
        acc[hh][ii].z = fmaf(pv, v4[hh].z, acc[hh][ii].z);
        acc[hh][ii].w = fmaf(pv, v4[hh].w, acc[hh][ii].w);
      }
  }
  // diag contributions (exactly once: wave 0, j8==0 lanes)
  if (w == 0 && j8 == 0) {
    #pragma unroll
    for (int ii = 0; ii < TI; ++ii) {
      const int ig = i0 + ii;
      if (ig >= station) {
        #pragma unroll
        for (int hh = 0; hh < HC; ++hh) {
          const float pv = p_smem[(hh * TI + ii) * S_ + ig];
          const float4 v4 = *reinterpret_cast<const float4*>(vb + hh * HS + ig * D_ + dc * 4);
          acc[hh][ii].x = fmaf(pv, v4.x, acc[hh][ii].x);
          acc[hh][ii].y = fmaf(pv, v4.y, acc[hh][ii].y);
          acc[hh][ii].z = fmaf(pv, v4.z, acc[hh][ii].z);
          acc[hh][ii].w = fmaf(pv, v4.w, acc[hh][ii].w);
        }
      }
    }
  }
  __syncthreads();   // p_smem reads done before reuse as redv

  // ---- reduce over (w, j8): shfl pair-sum then LDS tree (reuse p_smem) ----
  float4* redv = reinterpret_cast<float4*>(p_smem);
  #pragma unroll
  for (int hh = 0; hh < HC; ++hh)
    #pragma unroll
    for (int ii = 0; ii < TI; ++ii) {
      const int r = hh * TI + ii;
      float4 a = acc[hh][ii];
      a.x += __shfl_xor(a.x, 8);
      a.y += __shfl_xor(a.y, 8);
      a.z += __shfl_xor(a.z, 8);
      a.w += __shfl_xor(a.w, 8);
      if ((j8 & 1) == 0)
        redv[((w * 4 + (j8 >> 1)) * NR + r) * 8 + dc] = a;
    }
  __syncthreads();
  if (tid < NR * 8) {
    const int r = tid >> 3, d4 = tid & 7;
    float4 a = make_float4(0.f, 0.f, 0.f, 0.f);
    #pragma unroll
    for (int g = 0; g < 16; ++g) {
      const float4 x = redv[(g * NR + r) * 8 + d4];
      a.x += x.x; a.y += x.y; a.z += x.z; a.w += x.w;
    }
    const float inv = 1.f / sums[r];
    a.x *= inv; a.y *= inv; a.z *= inv; a.w *= inv;
    const int hh = r >> 1, ii = r & 1;             // TI == 2
    reinterpret_cast<float4*>(
        o_ws + (size_t)((b * H_ + h0 + hh) * S_ + i0 + ii) * D_)[d4] = a;
  }
}

// ---------------------------------------------------------------------------
// Kernel C: ctx = O @ fc_w + fc_b + hidden, then LayerNorm.
// grid = B*S/NROW, block = 256 (thread per output column m).
// ---------------------------------------------------------------------------
__global__ __launch_bounds__(256) void fc_ln_kernel(
    const float* __restrict__ o_ws, const float* __restrict__ fc_w,
    const float* __restrict__ fc_b, const float* __restrict__ hid,
    const float* __restrict__ ln_w, const float* __restrict__ ln_b,
    float* __restrict__ out)
{
  __shared__ float orow[NROW][HD_];
  __shared__ float red[NROW][4];
  const int tid = threadIdx.x;
  const int r0 = blockIdx.x * NROW;

  for (int idx = tid; idx < NROW * HD_; idx += 256) {
    const int r = idx >> 8, m = idx & 255;
    const int g = r0 + r;
    const int b = g >> 9, i = g & (S_ - 1);
    orow[r][m] = o_ws[((b * H_ + (m >> 5)) * S_ + i) * D_ + (m & 31)];
  }
  __syncthreads();

  float acc[NROW] = {0.f, 0.f, 0.f, 0.f};
  const float* wp = fc_w + tid;
  #pragma unroll 8
  for (int n4 = 0; n4 < HD_ / 4; ++n4) {
    const float w0 = wp[(4 * n4 + 0) * DM_];
    const float w1 = wp[(4 * n4 + 1) * DM_];
    const float w2 = wp[(4 * n4 + 2) * DM_];
    const float w3 = wp[(4 * n4 + 3) * DM_];
    #pragma unroll
    for (int r = 0; r < NROW; ++r) {
      const float4 ov = reinterpret_cast<const float4*>(&orow[r][0])[n4];
      acc[r] = fmaf(ov.x, w0, acc[r]);
      acc[r] = fmaf(ov.y, w1, acc[r]);
      acc[r] = fmaf(ov.z, w2, acc[r]);
      acc[r] = fmaf(ov.w, w3, acc[r]);
    }
  }
  const float bias = fc_b[tid];
  #pragma unroll
  for (int r = 0; r < NROW; ++r) acc[r] += bias + hid[(r0 + r) * DM_ + tid];

  // ---- LayerNorm over DM per row ----
  const int w = tid >> 6, lane = tid & 63;
  float mu[NROW];
  #pragma unroll
  for (int r = 0; r < NROW; ++r) {
    float s = acc[r];
    #pragma unroll
    for (int o = 32; o; o >>= 1) s += __shfl_xor(s, o, 64);
    if (lane == 0) red[r][w] = s;
  }
  __syncthreads();
  #pragma unroll
  for (int r = 0; r < NROW; ++r)
    mu[r] = (red[r][0] + red[r][1] + red[r][2] + red[r][3]) * (1.f / DM_);
  __syncthreads();
  #pragma unroll
  for (int r = 0; r < NROW; ++r) {
    const float dd = acc[r] - mu[r];
    float s = dd * dd;
    #pragma unroll
    for (int o = 32; o; o >>= 1) s += __shfl_xor(s, o, 64);
    if (lane == 0) red[r][w] = s;
  }
  __syncthreads();
  const float lw = ln_w[tid], lb = ln_b[tid];
  #pragma unroll
  for (int r = 0; r < NROW; ++r) {
    const float var = (red[r][0] + red[r][1] + red[r][2] + red[r][3]) * (1.f / DM_);
    out[(r0 + r) * DM_ + tid] =
        (acc[r] - mu[r]) * rsqrtf(var + 1e-6f) * lw + lb;
  }
}

// ---------------------------------------------------------------------------
extern "C" void kernel_launch(void* const* d_in, const int* in_sizes, int n_in,
                              void* d_out, int out_size, void* d_ws, size_t ws_size,
                              hipStream_t stream) {
  const float* hid = (const float*)d_in[0];
  const float* rpe = (const float*)d_in[1];
  const float* wq  = (const float*)d_in[2];
  const float* wk  = (const float*)d_in[3];
  const float* wv  = (const float*)d_in[4];
  const float* fcw = (const float*)d_in[5];
  const float* fcb = (const float*)d_in[6];
  const float* lnw = (const float*)d_in[7];
  const float* lnb = (const float*)d_in[8];
  const int* station = (const int*)d_in[9];
  float* out = (float*)d_out;

  const size_t per = (size_t)B_ * H_ * S_ * D_;   // 262144 floats
  float* q_ws = (float*)d_ws;
  float* k_ws = q_ws + per;
  float* v_ws = k_ws + per;
  float* o_ws = v_ws + per;

  dim3 gA(B_ * S_ / NROW, 3);
  qkv_kernel<<<gA, 256, 0, stream>>>(hid, wq, wk, wv, q_ws, k_ws, v_ws);
  attn_kernel<<<B_ * (S_ / TI) * (H_ / HC), 256, 0, stream>>>(
      rpe, q_ws, k_ws, v_ws, station, o_ws);
  fc_ln_kernel<<<B_ * S_ / NROW, 256, 0, stream>>>(o_ws, fcw, fcb, hid, lnw, lnb, out);
}